// Round 8
// baseline (28.891 us; speedup 1.0000x reference)
//
#include <hip/hip_runtime.h>
#include <math.h>

#define NKP 133
#define NROWS (256 * NKP)            // 34048 rows of 1024
#define RH_TOTAL (2 * NROWS)         // 68096 row-halves of 512
#define NQUADS (RH_TOTAL / 4)        // 17024 quads of 4 row-halves
#define NBLOCKS 2048
#define NWAVES (NBLOCKS * 4)         // 8192: q0=wid, q1=wid+8192, q2 if wid<640
#define C2P  14.4269504088896f       // 10*log2(e)
#define NK2  0.02251706f             // log2(e)/(2*5.66^2)
#define RAD  16.98f                  // 5.66*3
#define LN2f 0.69314718055994531f

static __device__ __forceinline__ float fexp2(float x) { return __builtin_amdgcn_exp2f(x); }
static __device__ __forceinline__ float frcp (float x) { return __builtin_amdgcn_rcpf(x); }

__global__ __launch_bounds__(256) void rtmcc_partial_kernel(
    const float* __restrict__ pred,       // [RH_TOTAL][512]
    const float* __restrict__ keypoints,  // [NROWS][3]
    float* __restrict__ partials)         // [NBLOCKS]
{
    const int wave = threadIdx.x >> 6;
    const int lane = threadIdx.x & 63;
    const int g    = lane >> 4;           // 16-lane group -> one row-half
    const int l4   = lane & 15;
    const int gh   = g >> 1;              // row within quad pair
    const int h    = g & 1;               // half: 0=x, 1=y
    __shared__ float2 twb[256];           // (e-1, e*g) at d = t-128; zero |d|>35
    __shared__ float lds[4];

    {   // build combined window table once per block
        const int t = threadIdx.x;
        const float d = (float)(t - 128);
        float em1 = 0.0f, eg = 0.0f;
        if (fabsf(d) <= 35.0f) {
            const float gg = fexp2(-d * d * NK2);   // gaussian target value
            const float e  = fexp2(gg * C2P);       // exp(10*g)
            em1 = e - 1.0f; eg = e * gg;
        }
        twb[t] = make_float2(em1, eg);
    }
    __syncthreads();

    const int wid = blockIdx.x * 4 + wave;      // 0..8191
    const int q0 = wid, q1 = wid + NWAVES, q2 = wid + 2 * NWAVES;
    const bool has3 = (q2 < NQUADS);            // wid < 640

    // ---- all keypoint loads issue immediately (independent) ----
    const int r0 = 2 * q0 + gh, r1 = 2 * q1 + gh;
    const float k0x = keypoints[r0*3+0], k0y = keypoints[r0*3+1], k0v = keypoints[r0*3+2];
    const float k1x = keypoints[r1*3+0], k1y = keypoints[r1*3+1], k1v = keypoints[r1*3+2];
    float k2x = 0.f, k2y = 0.f, k2v = 0.f;
    if (has3) {
        const int r2 = 2 * q2 + gh;
        k2x = keypoints[r2*3+0]; k2y = keypoints[r2*3+1]; k2v = keypoints[r2*3+2];
    }

    float acc = 0.0f;

    struct It { const float* ph; float w, mu; int mui, ws; bool act; };
    auto decode = [&](float kx, float ky, float kv, int q) {
        It it;
        const float mux = rintf(kx * 2.0f);     // half-to-even = jnp.round
        const float muy = rintf(ky * 2.0f);
        const bool oob = (mux - RAD >= 512.0f) || (muy - RAD >= 512.0f) ||
                         (mux + RAD + 1.0f < 0.0f) || (muy + RAD + 1.0f < 0.0f);
        const bool vis = (kv >= 0.5f);
        it.w   = (vis && oob) ? 0.0f : kv;
        it.act = (it.w > 0.0f);                 // uniform within 16-lane group
        it.mu  = h ? muy : mux;
        it.mui = (int)it.mu;
        int ws = it.mui - 64; it.ws = ws < 0 ? 0 : (ws > 384 ? 384 : ws);
        it.ph  = pred + (size_t)(4 * q + g) * 512;
        return it;
    };

    auto loadbulk = [&](const It& it, float4 (&qv)[8]) {
        if (it.act) {
            #pragma unroll
            for (int v = 0; v < 8; ++v)        // column-interleaved, coalesced
                qv[v] = *reinterpret_cast<const float4*>(it.ph + v * 64 + l4 * 4);
        }
    };

    auto compute = [&](const It& it, const float4 (&qv)[8]) {
        float s0 = 0.f, s1 = 0.f, r0 = 0.f, r1 = 0.f;   // dual chains
        #pragma unroll
        for (int v = 0; v < 8; v += 2) {
            s0 += fexp2(C2P*qv[v].x) + fexp2(C2P*qv[v].y)
                + fexp2(C2P*qv[v].z) + fexp2(C2P*qv[v].w);
            r0 -= (qv[v].x + qv[v].y) + (qv[v].z + qv[v].w);
            s1 += fexp2(C2P*qv[v+1].x) + fexp2(C2P*qv[v+1].y)
                + fexp2(C2P*qv[v+1].z) + fexp2(C2P*qv[v+1].w);
            r1 -= (qv[v+1].x + qv[v+1].y) + (qv[v+1].z + qv[v+1].w);
        }
        float S = s0 + s1, R = r0 + r1, Zw = 0.f;
        if (it.act) {   // window: 128 elems around mu, 8/lane, table lookups
            #pragma unroll
            for (int v = 0; v < 8; ++v) {
                const int idx = it.ws + l4 + v * 16;       // [ws, ws+128)
                const float pw = it.ph[idx];               // L1/L2-hot re-read
                int t = idx - it.mui + 128;
                t = t < 0 ? 0 : (t > 255 ? 255 : t);       // clamped entries are 0
                const float2 te = twb[t];                  // one ds_read_b64
                Zw += te.x;
                R  += te.y - te.x * pw;
            }
        }
        #pragma unroll
        for (int off = 1; off < 16; off <<= 1) {           // 4-step group butterfly
            S  += __shfl_xor(S,  off, 64);
            Zw += __shfl_xor(Zw, off, 64);
            R  += __shfl_xor(R,  off, 64);
        }
        if (it.act) {
            const float Z = 512.0f + Zw;                   // far-field e==1 exactly
            acc += it.w * (10.0f * R * frcp(Z) + (__log2f(S) - __log2f(Z)) * LN2f);
        }
    };

    // ---- static 2-stage pipeline: both iterations' loads before any compute ----
    const It it0 = decode(k0x, k0y, k0v, q0);
    const It it1 = decode(k1x, k1y, k1v, q1);
    float4 A[8], B[8];
    loadbulk(it0, A);
    loadbulk(it1, B);          // iter-1 latency hides under compute0's exp chain
    compute(it0, A);
    compute(it1, B);
    if (has3) {                // rare (640/8192 waves) serial third iteration
        const It it2 = decode(k2x, k2y, k2v, q2);
        loadbulk(it2, A);
        compute(it2, A);
    }

    // each group's loss sits in all 16 of its lanes -> /16 exact
    acc *= (1.0f / (16.0f * 512.0f * 133.0f));
    #pragma unroll
    for (int off = 1; off < 64; off <<= 1) acc += __shfl_xor(acc, off, 64);
    if (lane == 0) lds[wave] = acc;
    __syncthreads();
    if (threadIdx.x == 0)
        partials[blockIdx.x] = lds[0] + lds[1] + lds[2] + lds[3];
}

__global__ __launch_bounds__(256) void rtmcc_reduce_kernel(
    const float* __restrict__ partials, float* __restrict__ out)
{
    __shared__ float lds[4];
    float s = 0.0f;
    for (int i = threadIdx.x; i < NBLOCKS; i += 256) s += partials[i];
    #pragma unroll
    for (int off = 1; off < 64; off <<= 1) s += __shfl_xor(s, off, 64);
    if ((threadIdx.x & 63) == 0) lds[threadIdx.x >> 6] = s;
    __syncthreads();
    if (threadIdx.x == 0) out[0] = lds[0] + lds[1] + lds[2] + lds[3];
}

extern "C" void kernel_launch(void* const* d_in, const int* in_sizes, int n_in,
                              void* d_out, int out_size, void* d_ws, size_t ws_size,
                              hipStream_t stream) {
    const float* pred = (const float*)d_in[0];   // (256,133,1024) fp32
    const float* kpts = (const float*)d_in[1];   // (256,133,3) fp32
    float* out = (float*)d_out;
    float* partials = (float*)d_ws;

    rtmcc_partial_kernel<<<NBLOCKS, 256, 0, stream>>>(pred, kpts, partials);
    rtmcc_reduce_kernel<<<1, 256, 0, stream>>>(partials, out);
}

// Round 9
// 27.957 us; speedup vs baseline: 1.0334x; 1.0334x over previous
//
#include <hip/hip_runtime.h>
#include <math.h>

#define NKP 133
#define NROWS (256 * NKP)            // 34048 rows of 1024
#define RH_TOTAL (2 * NROWS)         // 68096 row-halves of 512
#define NQUADS (RH_TOTAL / 4)        // 17024 quads (4 row-halves each)
#define NBLOCKS (NQUADS / 4)         // 4256 blocks, 4 waves each, ONE quad per wave
#define C2P  14.4269504088896f       // 10*log2(e): exp(10x)=exp2(C2P*x)
#define NK2  0.02251706f             // log2(e)/(2*5.66^2)
#define RAD  16.98f                  // 5.66*3
#define LN2f 0.69314718055994531f

static __device__ __forceinline__ float fexp2(float x) { return __builtin_amdgcn_exp2f(x); }
static __device__ __forceinline__ float frcp (float x) { return __builtin_amdgcn_rcpf(x); }

// v_add_f32 with DPP row_shr:N (16-lane row == our group), zero-fill OOB.
// After shr 1,2,4,8 lane15 of each row holds the 16-lane sum.
#define DPP_SHR_ADD(x, CTRL)                                                   \
    x += __int_as_float(__builtin_amdgcn_update_dpp(                           \
            0, __float_as_int(x), (CTRL), 0xf, 0xf, true))
#define GROUP_SUM(x) do {                                                      \
    DPP_SHR_ADD(x, 0x111);  /* row_shr:1 */                                    \
    DPP_SHR_ADD(x, 0x112);  /* row_shr:2 */                                    \
    DPP_SHR_ADD(x, 0x114);  /* row_shr:4 */                                    \
    DPP_SHR_ADD(x, 0x118);  /* row_shr:8 */                                    \
} while (0)

__global__ __launch_bounds__(256) void rtmcc_partial_kernel(
    const float* __restrict__ pred,       // [RH_TOTAL][512]
    const float* __restrict__ keypoints,  // [NROWS][3]
    float* __restrict__ partials)         // [NBLOCKS]
{
    const int wave = threadIdx.x >> 6;
    const int lane = threadIdx.x & 63;
    const int g    = lane >> 4;           // 16-lane group -> one row-half
    const int l4   = lane & 15;
    const int gh   = g >> 1;              // row within quad pair
    const int h    = g & 1;               // half: 0=x, 1=y
    __shared__ float2 twb[256];           // (e-1, e*g) at d=t-128; zero |d|>35
    __shared__ float lds[4];

    // ---- keypoint loads FIRST: latency hides under table build + sync ----
    const int q   = blockIdx.x * 4 + wave;     // 0..17023, exact cover
    const int row = 2 * q + gh;
    const float kx = keypoints[row * 3 + 0];
    const float ky = keypoints[row * 3 + 1];
    const float kv = keypoints[row * 3 + 2];

    {   // window table once per block
        const int t = threadIdx.x;
        const float d = (float)(t - 128);
        float em1 = 0.0f, eg = 0.0f;
        if (fabsf(d) <= 35.0f) {
            const float gg = fexp2(-d * d * NK2);   // gaussian target
            const float e  = fexp2(gg * C2P);       // exp(10*g)
            em1 = e - 1.0f; eg = e * gg;
        }
        twb[t] = make_float2(em1, eg);
    }
    __syncthreads();

    // ---- decode ----
    const float mux = rintf(kx * 2.0f);        // half-to-even = jnp.round
    const float muy = rintf(ky * 2.0f);
    const bool oob = (mux - RAD >= 512.0f) || (muy - RAD >= 512.0f) ||
                     (mux + RAD + 1.0f < 0.0f) || (muy + RAD + 1.0f < 0.0f);
    const bool visible = (kv >= 0.5f);
    const float w = (visible && oob) ? 0.0f : kv;
    const bool act = (w > 0.0f);               // uniform within 16-lane group

    float S = 0.0f, Zw = 0.0f, R = 0.0f;
    if (act) {
        const float* ph = pred + (size_t)(4 * q + g) * 512;

        // ---- bulk: 8 float4 loads, column-interleaved (each load = 4x1KB
        //      contiguous segments per wave, fully coalesced) ----
        float4 qv[8];
        #pragma unroll
        for (int v = 0; v < 8; ++v)
            qv[v] = *reinterpret_cast<const float4*>(ph + v * 64 + l4 * 4);

        float s0 = 0.f, s1 = 0.f, r0 = 0.f, r1 = 0.f;   // dual chains
        #pragma unroll
        for (int v = 0; v < 8; v += 2) {
            s0 += fexp2(C2P*qv[v].x)   + fexp2(C2P*qv[v].y)
                + fexp2(C2P*qv[v].z)   + fexp2(C2P*qv[v].w);
            r0 -= (qv[v].x + qv[v].y) + (qv[v].z + qv[v].w);
            s1 += fexp2(C2P*qv[v+1].x) + fexp2(C2P*qv[v+1].y)
                + fexp2(C2P*qv[v+1].z) + fexp2(C2P*qv[v+1].w);
            r1 -= (qv[v+1].x + qv[v+1].y) + (qv[v+1].z + qv[v+1].w);
        }
        S = s0 + s1; R = r0 + r1;

        // ---- window: 128 elems around mu, 8/lane, LDS table lookups ----
        const float mu = h ? muy : mux;
        const int mui = (int)mu;
        int ws = mui - 64; ws = ws < 0 ? 0 : (ws > 384 ? 384 : ws);
        #pragma unroll
        for (int v = 0; v < 8; ++v) {
            const int idx = ws + l4 + v * 16;      // [ws, ws+128)
            const float pw = ph[idx];              // L1-hot re-read
            int t = idx - mui + 128;
            t = t < 0 ? 0 : (t > 255 ? 255 : t);   // clamped entries are 0
            const float2 te = twb[t];              // ds_read_b64
            Zw += te.x;
            R  += te.y - te.x * pw;
        }
    }

    // ---- 16-lane group sums via DPP (VALU pipe, short chain) ----
    GROUP_SUM(S);
    GROUP_SUM(Zw);
    GROUP_SUM(R);

    float accv = 0.0f;
    if (act && l4 == 15) {                     // lane15 holds the group totals
        const float Z = 512.0f + Zw;           // far-field e == 1.0f exactly
        accv = w * (10.0f * R * frcp(Z) + (__log2f(S) - __log2f(Z)) * LN2f)
                 * (1.0f / (512.0f * 133.0f));
    }

    // ---- wave butterfly (once per wave) + block sum ----
    #pragma unroll
    for (int off = 1; off < 64; off <<= 1) accv += __shfl_xor(accv, off, 64);
    if (lane == 0) lds[wave] = accv;
    __syncthreads();
    if (threadIdx.x == 0)
        partials[blockIdx.x] = lds[0] + lds[1] + lds[2] + lds[3];
}

__global__ __launch_bounds__(256) void rtmcc_reduce_kernel(
    const float* __restrict__ partials, float* __restrict__ out)
{
    __shared__ float lds[4];
    float s = 0.0f;
    for (int i = threadIdx.x; i < NBLOCKS; i += 256) s += partials[i];
    #pragma unroll
    for (int off = 1; off < 64; off <<= 1) s += __shfl_xor(s, off, 64);
    if ((threadIdx.x & 63) == 0) lds[threadIdx.x >> 6] = s;
    __syncthreads();
    if (threadIdx.x == 0) out[0] = lds[0] + lds[1] + lds[2] + lds[3];
}

extern "C" void kernel_launch(void* const* d_in, const int* in_sizes, int n_in,
                              void* d_out, int out_size, void* d_ws, size_t ws_size,
                              hipStream_t stream) {
    const float* pred = (const float*)d_in[0];   // (256,133,1024) fp32
    const float* kpts = (const float*)d_in[1];   // (256,133,3) fp32
    float* out = (float*)d_out;
    float* partials = (float*)d_ws;

    rtmcc_partial_kernel<<<NBLOCKS, 256, 0, stream>>>(pred, kpts, partials);
    rtmcc_reduce_kernel<<<1, 256, 0, stream>>>(partials, out);
}